// Round 4
// baseline (12834.068 us; speedup 1.0000x reference)
//
#include <hip/hip_runtime.h>
#include <math.h>

typedef __bf16 bf16;
typedef __attribute__((ext_vector_type(8))) __bf16 bf16x8;
typedef __attribute__((ext_vector_type(4))) float f32x4;

// ---------------------------------------------------------------------------
// Inputs are fp32 (reference dtype). One-time prep: transpose+convert gate
// weights to bf16 WT[(g*1024+j)][1536], convert embed to bf16.
// ---------------------------------------------------------------------------

__global__ __launch_bounds__(256) void k_zero(unsigned* __restrict__ p, int n) {
  int i = blockIdx.x * 256 + threadIdx.x;
  if (i < n) p[i] = 0u;
}

// dst[j][k] = (bf16) src[k][j];  src fp32 [1536][1024] (gate z), dst row-stride 1536.
__global__ __launch_bounds__(256) void k_wt(const float* __restrict__ Wf,
                                            const float* __restrict__ Wi,
                                            const float* __restrict__ Wc,
                                            const float* __restrict__ Wo,
                                            bf16* __restrict__ WT) {
  __shared__ __align__(16) float tile[64][68];
  int g = blockIdx.z;
  const float* src = g == 0 ? Wf : g == 1 ? Wi : g == 2 ? Wc : Wo;
  bf16* dst = WT + (size_t)g * 1024 * 1536;
  int t = threadIdx.x;
  int r0 = blockIdx.x * 64, c0 = blockIdx.y * 64;   // r: k-dim (1536), c: j-dim (1024)
  int r = t >> 2, cs = (t & 3) * 16;
  const f32x4* s = (const f32x4*)(src + (size_t)(r0 + r) * 1024 + c0 + cs);
#pragma unroll
  for (int i = 0; i < 4; i++) *(f32x4*)&tile[r][cs + i * 4] = s[i];
  __syncthreads();
  int c = t >> 2, rs = (t & 3) * 16;
  bf16x8 v0, v1;
#pragma unroll
  for (int i = 0; i < 8; i++) v0[i] = (bf16)tile[rs + i][c];
#pragma unroll
  for (int i = 0; i < 8; i++) v1[i] = (bf16)tile[rs + 8 + i][c];
  bf16* d = dst + (size_t)(c0 + c) * 1536 + r0 + rs;
  *(bf16x8*)d       = v0;
  *(bf16x8*)(d + 8) = v1;
}

// embB = (bf16) embed, 16,384,000 elems; 8 per thread.
__global__ __launch_bounds__(256) void k_cvt(const float* __restrict__ src,
                                             bf16* __restrict__ dst) {
  size_t i = ((size_t)blockIdx.x * 256 + threadIdx.x) * 8;
  f32x4 a = *(const f32x4*)(src + i);
  f32x4 b = *(const f32x4*)(src + i + 4);
  bf16x8 o;
#pragma unroll
  for (int r = 0; r < 4; r++) { o[r] = (bf16)a[r]; o[4 + r] = (bf16)b[r]; }
  *(bf16x8*)(dst + i) = o;
}

// ---------------------------------------------------------------------------
// Persistent LSTM recurrence, x-projection fused (K = 512 x + 1024 h).
// 256 blocks = 4 batch-groups x 64 column-owners; wave = gate.
// Block (gb,wg): batch rows gb*16..+16, h-cols wg*16..+16.
// Gate weights in VGPRs: 48 bf16x8 frags/thread (192 VGPR, 1 wave/SIMD).
// h ping-pongs in global bf16; groups sync via atomic counter + agent fences.
// ---------------------------------------------------------------------------
__global__ __launch_bounds__(256, 1) void k_lstm(const int* __restrict__ ids,
                                                 const bf16* __restrict__ embB,
                                                 const bf16* __restrict__ WT,
                                                 const float* __restrict__ bfp,
                                                 const float* __restrict__ bip,
                                                 const float* __restrict__ bcp,
                                                 const float* __restrict__ bop,
                                                 bf16* __restrict__ hbuf,
                                                 unsigned* __restrict__ cnt) {
  int blk = blockIdx.x;
  int gb = blk >> 6, wgid = blk & 63, j0 = wgid * 16;
  int t = threadIdx.x, l = t & 63, wave = t >> 6;
  int q = l >> 4, rl = l & 15;
  __shared__ __align__(16) bf16 sx[16 * 520];
  __shared__ __align__(16) bf16 sh[16 * 1032];
  __shared__ float act[4][16][16];
  __shared__ float cst[16][16];
  cst[t >> 4][t & 15] = 0.f;

  const bf16* wrow = WT + (size_t)(wave * 1024 + j0 + rl) * 1536;
  bf16x8 wx[16], wh[32];
#pragma unroll
  for (int ks = 0; ks < 16; ++ks) wx[ks] = *(const bf16x8*)(wrow + ks * 32 + q * 8);
#pragma unroll
  for (int ks = 0; ks < 32; ++ks) wh[ks] = *(const bf16x8*)(wrow + 512 + ks * 32 + q * 8);
  const float* bias_p = wave == 0 ? bfp : wave == 1 ? bip : wave == 2 ? bcp : bop;
  float bv = bias_p[j0 + rl];

  unsigned* mycnt = cnt + gb;

  for (int ts = 0; ts < 512; ++ts) {
    const bf16* rbuf = hbuf + (ts & 1) * 65536;
    bf16* wbuf = hbuf + ((ts + 1) & 1) * 65536;
    // stage x slab [16][512] from gathered embB rows
#pragma unroll
    for (int i = 0; i < 4; i++) {
      int c = i * 256 + t;
      int mm = c >> 6, kc = c & 63;
      int tok = ids[(gb * 16 + mm) * 512 + ts];
      *(bf16x8*)(sx + mm * 520 + kc * 8) =
          *(const bf16x8*)(embB + (size_t)tok * 512 + kc * 8);
    }
    // stage h slab [16][1024]
#pragma unroll
    for (int i = 0; i < 8; i++) {
      int c = i * 256 + t;
      int mm = c >> 7, kc = c & 127;
      *(bf16x8*)(sh + mm * 1032 + kc * 8) =
          *(const bf16x8*)(rbuf + (size_t)(gb * 16 + mm) * 1024 + kc * 8);
    }
    __syncthreads();
    // preact [16 b x 16 j] for gate = wave; A-frag rows = rl, k = ks*32+q*8+j
    f32x4 acc0 = {0.f, 0.f, 0.f, 0.f}, acc1 = {0.f, 0.f, 0.f, 0.f};
    const bf16* xrow = sx + rl * 520;
    const bf16* hrow = sh + rl * 1032;
#pragma unroll
    for (int ks = 0; ks < 16; ks += 2) {
      bf16x8 a0 = *(const bf16x8*)(xrow + ks * 32 + q * 8);
      bf16x8 a1 = *(const bf16x8*)(xrow + (ks + 1) * 32 + q * 8);
      acc0 = __builtin_amdgcn_mfma_f32_16x16x32_bf16(a0, wx[ks], acc0, 0, 0, 0);
      acc1 = __builtin_amdgcn_mfma_f32_16x16x32_bf16(a1, wx[ks + 1], acc1, 0, 0, 0);
    }
#pragma unroll
    for (int ks = 0; ks < 32; ks += 2) {
      bf16x8 a0 = *(const bf16x8*)(hrow + ks * 32 + q * 8);
      bf16x8 a1 = *(const bf16x8*)(hrow + (ks + 1) * 32 + q * 8);
      acc0 = __builtin_amdgcn_mfma_f32_16x16x32_bf16(a0, wh[ks], acc0, 0, 0, 0);
      acc1 = __builtin_amdgcn_mfma_f32_16x16x32_bf16(a1, wh[ks + 1], acc1, 0, 0, 0);
    }
    f32x4 pre = acc0 + acc1;
    f32x4 av = {};
    if (wave == 2) {           // g gate: tanh
#pragma unroll
      for (int r = 0; r < 4; r++) {
        float x = fminf(fmaxf(pre[r] + bv, -20.f), 20.f);
        float e = __expf(-2.f * x);
        av[r] = (1.f - e) / (1.f + e);
      }
    } else {                   // f,i,o: sigmoid
#pragma unroll
      for (int r = 0; r < 4; r++) {
        float x = fminf(fmaxf(pre[r] + bv, -30.f), 30.f);
        av[r] = 1.f / (1.f + __expf(-x));
      }
    }
#pragma unroll
    for (int r = 0; r < 4; r++) act[wave][q * 4 + r][rl] = av[r];   // row=q*4+r, col=rl
    __syncthreads();
    // pointwise update, one thread per (m,n)
    {
      int m = t >> 4, n = t & 15;
      float f = act[0][m][n], i2 = act[1][m][n], g = act[2][m][n], o = act[3][m][n];
      float c = cst[m][n] * f + g * i2;
      cst[m][n] = c;
      wbuf[(size_t)(gb * 16 + m) * 1024 + j0 + n] = (bf16)(c * o);
    }
    __syncthreads();
    // per-group inter-block barrier
    if (t == 0) {
      __builtin_amdgcn_fence(__ATOMIC_RELEASE, "agent");
      __hip_atomic_fetch_add(mycnt, 1u, __ATOMIC_RELEASE, __HIP_MEMORY_SCOPE_AGENT);
      unsigned tgt = 64u * (unsigned)(ts + 1);
      while (__hip_atomic_load(mycnt, __ATOMIC_ACQUIRE, __HIP_MEMORY_SCOPE_AGENT) < tgt)
        __builtin_amdgcn_s_sleep(1);
    }
    __syncthreads();
    __builtin_amdgcn_fence(__ATOMIC_ACQUIRE, "agent");
  }
}

// ---------------------------------------------------------------------------
// Final logits, fp32 VALU: out[b][v] = sum_k h[b][k]*Wout[k][v] + bout[v].
// grid(125, 2): 256 v-cols x 32 batch per block; h (bf16) staged in LDS.
// ---------------------------------------------------------------------------
__global__ __launch_bounds__(256) void k_final(const bf16* __restrict__ h,
                                               const float* __restrict__ Wout,
                                               const float* __restrict__ boutp,
                                               float* __restrict__ out) {
  int t = threadIdx.x;
  int v = blockIdx.x * 256 + t;            // 0..31999
  int b0 = blockIdx.y * 32;
  __shared__ __align__(16) bf16 shf[32 * 1024];   // 64 KB
#pragma unroll
  for (int i = 0; i < 16; i++) {
    int c = i * 256 + t;
    int mm = c >> 7, kc = c & 127;
    *(bf16x8*)(shf + mm * 1024 + kc * 8) =
        *(const bf16x8*)(h + (size_t)(b0 + mm) * 1024 + kc * 8);
  }
  __syncthreads();
  float acc[32];
  float bb = boutp[v];
#pragma unroll
  for (int mm = 0; mm < 32; mm++) acc[mm] = bb;
  for (int k = 0; k < 1024; k++) {
    float wv = Wout[(size_t)k * 32000 + v];
#pragma unroll
    for (int mm = 0; mm < 32; mm++) acc[mm] += (float)shf[mm * 1024 + k] * wv;
  }
#pragma unroll
  for (int mm = 0; mm < 32; mm++)
    out[(size_t)(b0 + mm) * 32000 + v] = acc[mm];
}

// ---------------------------------------------------------------------------
// Workspace (bytes), total 45,613,312:
//   WT   @ 0        : 4096*1536*2  = 12,582,912  (bf16 transposed gate weights)
//   embB @ 12582912 : 32000*512*2  = 32,768,000  (bf16 embedding)
//   hbuf @ 45350912 : 2*64*1024*2  =    262,144  (bf16 h ping-pong, zeroed)
//   cnt  @ 45613056 : 256                         (barrier counters, zeroed)
// ---------------------------------------------------------------------------
extern "C" void kernel_launch(void* const* d_in, const int* in_sizes, int n_in,
                              void* d_out, int out_size, void* d_ws, size_t ws_size,
                              hipStream_t stream) {
  const int*   ids   = (const int*)d_in[0];
  const float* embed = (const float*)d_in[1];
  const float* Wf    = (const float*)d_in[2];
  const float* bfp   = (const float*)d_in[3];
  const float* Wi    = (const float*)d_in[4];
  const float* bip   = (const float*)d_in[5];
  const float* Wc    = (const float*)d_in[6];
  const float* bcp   = (const float*)d_in[7];
  const float* Wo    = (const float*)d_in[8];
  const float* bop   = (const float*)d_in[9];
  const float* Wout  = (const float*)d_in[10];
  const float* bout  = (const float*)d_in[11];
  float* out = (float*)d_out;

  char* ws = (char*)d_ws;
  bf16*     WT   = (bf16*)(ws);
  bf16*     embB = (bf16*)(ws + 12582912ull);
  bf16*     hbuf = (bf16*)(ws + 45350912ull);
  unsigned* cnt  = (unsigned*)(ws + 45613056ull);

  k_zero<<<257, 256, 0, stream>>>((unsigned*)(ws + 45350912ull), 65600);
  k_wt<<<dim3(24, 16, 4), 256, 0, stream>>>(Wf, Wi, Wc, Wo, WT);
  k_cvt<<<8000, 256, 0, stream>>>(embed, embB);
  k_lstm<<<256, 256, 0, stream>>>(ids, embB, WT, bfp, bip, bcp, bop, hbuf, cnt);
  k_final<<<dim3(125, 2), 256, 0, stream>>>(hbuf, Wout, bout, out);
}

// Round 5
// 3730.677 us; speedup vs baseline: 3.4401x; 3.4401x over previous
//
#include <hip/hip_runtime.h>
#include <math.h>

typedef __bf16 bf16;
typedef unsigned long long ull;
typedef __attribute__((ext_vector_type(8))) __bf16 bf16x8;
typedef __attribute__((ext_vector_type(4))) float f32x4;

__global__ __launch_bounds__(256) void k_zero(unsigned* __restrict__ p, int n) {
  int i = blockIdx.x * 256 + threadIdx.x;
  if (i < n) p[i] = 0u;
}

// dst[j][k] = (bf16) src[k][j];  src fp32 [1536][1024] per gate, dst stride 1536.
__global__ __launch_bounds__(256) void k_wt(const float* __restrict__ Wf,
                                            const float* __restrict__ Wi,
                                            const float* __restrict__ Wc,
                                            const float* __restrict__ Wo,
                                            bf16* __restrict__ WT) {
  __shared__ __align__(16) float tile[64][68];
  int g = blockIdx.z;
  const float* src = g == 0 ? Wf : g == 1 ? Wi : g == 2 ? Wc : Wo;
  bf16* dst = WT + (size_t)g * 1024 * 1536;
  int t = threadIdx.x;
  int r0 = blockIdx.x * 64, c0 = blockIdx.y * 64;
  int r = t >> 2, cs = (t & 3) * 16;
  const f32x4* s = (const f32x4*)(src + (size_t)(r0 + r) * 1024 + c0 + cs);
#pragma unroll
  for (int i = 0; i < 4; i++) *(f32x4*)&tile[r][cs + i * 4] = s[i];
  __syncthreads();
  int c = t >> 2, rs = (t & 3) * 16;
  bf16x8 v0, v1;
#pragma unroll
  for (int i = 0; i < 8; i++) v0[i] = (bf16)tile[rs + i][c];
#pragma unroll
  for (int i = 0; i < 8; i++) v1[i] = (bf16)tile[rs + 8 + i][c];
  bf16* d = dst + (size_t)(c0 + c) * 1536 + r0 + rs;
  *(bf16x8*)d       = v0;
  *(bf16x8*)(d + 8) = v1;
}

__global__ __launch_bounds__(256) void k_cvt(const float* __restrict__ src,
                                             bf16* __restrict__ dst) {
  size_t i = ((size_t)blockIdx.x * 256 + threadIdx.x) * 8;
  f32x4 a = *(const f32x4*)(src + i);
  f32x4 b = *(const f32x4*)(src + i + 4);
  bf16x8 o;
#pragma unroll
  for (int r = 0; r < 4; r++) { o[r] = (bf16)a[r]; o[4 + r] = (bf16)b[r]; }
  *(bf16x8*)(dst + i) = o;
}

// ---------------------------------------------------------------------------
// Persistent LSTM recurrence.  256 blocks = 4 batch-groups x 64 column-owners;
// wave = gate; block owns 16 h-cols x 16 batch rows.  Weights in regs.
// Sync protocol (NO agent fences — they buffer_inv the XCD L2 on gfx9xx):
//   h exchanged via RELAXED agent-scope 8B atomics (sc1: L2-bypass, L3-coherent)
//   per-group monotonic counter, RELAXED add/poll, 128B-strided
//   __syncthreads drains stores pre-add; workgroup acquire fence post-poll
// x-projection (h-independent) software-pipelined into the barrier wait.
// ---------------------------------------------------------------------------
__global__ __launch_bounds__(256, 1) void k_lstm(const int* __restrict__ ids,
                                                 const bf16* __restrict__ embB,
                                                 const bf16* __restrict__ WT,
                                                 const float* __restrict__ bfp,
                                                 const float* __restrict__ bip,
                                                 const float* __restrict__ bcp,
                                                 const float* __restrict__ bop,
                                                 bf16* __restrict__ hbuf,
                                                 unsigned* __restrict__ cnt) {
  int blk = blockIdx.x;
  int gb = blk >> 6, wgid = blk & 63, j0 = wgid * 16;
  int t = threadIdx.x, l = t & 63, wave = t >> 6;
  int q = l >> 4, rl = l & 15;
  __shared__ __align__(16) bf16 sx[16 * 520];
  __shared__ __align__(16) bf16 sh[16 * 1032];
  __shared__ float act[4][16][16];
  __shared__ float cst[16][16];
  __shared__ __align__(8) bf16 hsh[16][16];
  cst[t >> 4][t & 15] = 0.f;

  const bf16* wrow = WT + (size_t)(wave * 1024 + j0 + rl) * 1536;
  bf16x8 wx[16], wh[32];
#pragma unroll
  for (int ks = 0; ks < 16; ++ks) wx[ks] = *(const bf16x8*)(wrow + ks * 32 + q * 8);
#pragma unroll
  for (int ks = 0; ks < 32; ++ks) wh[ks] = *(const bf16x8*)(wrow + 512 + ks * 32 + q * 8);
  const float* bias_p = wave == 0 ? bfp : wave == 1 ? bip : wave == 2 ? bcp : bop;
  float bv = bias_p[j0 + rl];

  unsigned* mycnt = cnt + gb * 32;   // 128B apart

  // ---- prologue: stage x slab for ts=0 and run its MFMAs ----
  f32x4 xa0 = {0.f, 0.f, 0.f, 0.f}, xa1 = {0.f, 0.f, 0.f, 0.f};
#pragma unroll
  for (int i = 0; i < 4; i++) {
    int c = i * 256 + t;
    int mm = c >> 6, kc = c & 63;
    int tok = ids[(gb * 16 + mm) * 512 + 0];
    *(bf16x8*)(sx + mm * 520 + kc * 8) =
        *(const bf16x8*)(embB + (size_t)tok * 512 + kc * 8);
  }
  __syncthreads();
  {
    const bf16* xrow = sx + rl * 520;
#pragma unroll
    for (int ks = 0; ks < 16; ks += 2) {
      bf16x8 a0 = *(const bf16x8*)(xrow + ks * 32 + q * 8);
      bf16x8 a1 = *(const bf16x8*)(xrow + (ks + 1) * 32 + q * 8);
      xa0 = __builtin_amdgcn_mfma_f32_16x16x32_bf16(a0, wx[ks], xa0, 0, 0, 0);
      xa1 = __builtin_amdgcn_mfma_f32_16x16x32_bf16(a1, wx[ks + 1], xa1, 0, 0, 0);
    }
  }

  for (int ts = 0; ts < 512; ++ts) {
    const bf16* rbuf = hbuf + (ts & 1) * 65536;
    bf16* wbuf = hbuf + ((ts + 1) & 1) * 65536;

    // stage h slab [16][1024] via coherent (sc1) 8B atomic loads -> LDS
#pragma unroll
    for (int i = 0; i < 16; i++) {
      int chunk = i * 256 + t;               // 0..4095, 4 bf16 each
      int mm = chunk >> 8, kc4 = (chunk & 255) * 4;
      ull v = __hip_atomic_load(
          (const ull*)(rbuf + (size_t)(gb * 16 + mm) * 1024 + kc4),
          __ATOMIC_RELAXED, __HIP_MEMORY_SCOPE_AGENT);
      *(ull*)(sh + mm * 1032 + kc4) = v;
    }
    __syncthreads();

    // h-part MFMAs on top of pipelined x-part accumulators
    f32x4 acc0 = xa0, acc1 = xa1;
    {
      const bf16* hrow = sh + rl * 1032;
#pragma unroll
      for (int ks = 0; ks < 32; ks += 2) {
        bf16x8 a0 = *(const bf16x8*)(hrow + ks * 32 + q * 8);
        bf16x8 a1 = *(const bf16x8*)(hrow + (ks + 1) * 32 + q * 8);
        acc0 = __builtin_amdgcn_mfma_f32_16x16x32_bf16(a0, wh[ks], acc0, 0, 0, 0);
        acc1 = __builtin_amdgcn_mfma_f32_16x16x32_bf16(a1, wh[ks + 1], acc1, 0, 0, 0);
      }
    }
    f32x4 pre = acc0 + acc1;
    f32x4 av = {};
    if (wave == 2) {           // g gate: tanh
#pragma unroll
      for (int r = 0; r < 4; r++) {
        float x = fminf(fmaxf(pre[r] + bv, -20.f), 20.f);
        float e = __expf(-2.f * x);
        av[r] = (1.f - e) / (1.f + e);
      }
    } else {                   // f,i,o: sigmoid
#pragma unroll
      for (int r = 0; r < 4; r++) {
        float x = fminf(fmaxf(pre[r] + bv, -30.f), 30.f);
        av[r] = 1.f / (1.f + __expf(-x));
      }
    }
#pragma unroll
    for (int r = 0; r < 4; r++) act[wave][q * 4 + r][rl] = av[r];
    __syncthreads();
    // pointwise update -> hsh (bf16)
    {
      int m = t >> 4, n = t & 15;
      float f = act[0][m][n], i2 = act[1][m][n], g = act[2][m][n], o = act[3][m][n];
      float c = cst[m][n] * f + g * i2;
      cst[m][n] = c;
      hsh[m][n] = (bf16)(c * o);
    }
    __syncthreads();
    // publish h: 64 threads x 8B coherent stores
    if (t < 64) {
      int mm = t >> 2, qd = t & 3;
      __hip_atomic_store(
          (ull*)(wbuf + (size_t)(gb * 16 + mm) * 1024 + j0 + qd * 4),
          *(const ull*)&hsh[mm][qd * 4],
          __ATOMIC_RELAXED, __HIP_MEMORY_SCOPE_AGENT);
    }
    __syncthreads();   // drains vmcnt before barrier -> stores globally visible
    if (t == 0)
      __hip_atomic_fetch_add(mycnt, 1u, __ATOMIC_RELAXED, __HIP_MEMORY_SCOPE_AGENT);

    // ---- overlap: stage + compute x-part for ts+1 while counter propagates
    if (ts < 511) {
      xa0 = {0.f, 0.f, 0.f, 0.f}; xa1 = {0.f, 0.f, 0.f, 0.f};
#pragma unroll
      for (int i = 0; i < 4; i++) {
        int c = i * 256 + t;
        int mm = c >> 6, kc = c & 63;
        int tok = ids[(gb * 16 + mm) * 512 + ts + 1];
        *(bf16x8*)(sx + mm * 520 + kc * 8) =
            *(const bf16x8*)(embB + (size_t)tok * 512 + kc * 8);
      }
      __syncthreads();
      const bf16* xrow = sx + rl * 520;
#pragma unroll
      for (int ks = 0; ks < 16; ks += 2) {
        bf16x8 a0 = *(const bf16x8*)(xrow + ks * 32 + q * 8);
        bf16x8 a1 = *(const bf16x8*)(xrow + (ks + 1) * 32 + q * 8);
        xa0 = __builtin_amdgcn_mfma_f32_16x16x32_bf16(a0, wx[ks], xa0, 0, 0, 0);
        xa1 = __builtin_amdgcn_mfma_f32_16x16x32_bf16(a1, wx[ks + 1], xa1, 0, 0, 0);
      }
    }

    // poll (relaxed — no per-poll cache invalidation)
    if (t == 0) {
      unsigned tgt = 64u * (unsigned)(ts + 1);
      while (__hip_atomic_load(mycnt, __ATOMIC_RELAXED, __HIP_MEMORY_SCOPE_AGENT) < tgt)
        __builtin_amdgcn_s_sleep(1);
    }
    __syncthreads();
    __builtin_amdgcn_fence(__ATOMIC_ACQUIRE, "workgroup");  // compiler ordering only
  }
}

// ---------------------------------------------------------------------------
// Final logits, fp32 VALU: out[b][v] = sum_k h[b][k]*Wout[k][v] + bout[v].
// ---------------------------------------------------------------------------
__global__ __launch_bounds__(256) void k_final(const bf16* __restrict__ h,
                                               const float* __restrict__ Wout,
                                               const float* __restrict__ boutp,
                                               float* __restrict__ out) {
  int t = threadIdx.x;
  int v = blockIdx.x * 256 + t;
  int b0 = blockIdx.y * 32;
  __shared__ __align__(16) bf16 shf[32 * 1024];
#pragma unroll
  for (int i = 0; i < 16; i++) {
    int c = i * 256 + t;
    int mm = c >> 7, kc = c & 127;
    *(bf16x8*)(shf + mm * 1024 + kc * 8) =
        *(const bf16x8*)(h + (size_t)(b0 + mm) * 1024 + kc * 8);
  }
  __syncthreads();
  float acc[32];
  float bb = boutp[v];
#pragma unroll
  for (int mm = 0; mm < 32; mm++) acc[mm] = bb;
  for (int k = 0; k < 1024; k++) {
    float wv = Wout[(size_t)k * 32000 + v];
#pragma unroll
    for (int mm = 0; mm < 32; mm++) acc[mm] += (float)shf[mm * 1024 + k] * wv;
  }
#pragma unroll
  for (int mm = 0; mm < 32; mm++)
    out[(size_t)(b0 + mm) * 32000 + v] = acc[mm];
}

// ---------------------------------------------------------------------------
// Workspace (bytes), total 45,614,080:
//   WT   @ 0        : 4096*1536*2  = 12,582,912
//   embB @ 12582912 : 32000*512*2  = 32,768,000
//   hbuf @ 45350912 : 2*64*1024*2  =    262,144  (zeroed)
//   cnt  @ 45613056 : 1024  (4 counters, 128B-strided, zeroed)
// ---------------------------------------------------------------------------
extern "C" void kernel_launch(void* const* d_in, const int* in_sizes, int n_in,
                              void* d_out, int out_size, void* d_ws, size_t ws_size,
                              hipStream_t stream) {
  const int*   ids   = (const int*)d_in[0];
  const float* embed = (const float*)d_in[1];
  const float* Wf    = (const float*)d_in[2];
  const float* bfp   = (const float*)d_in[3];
  const float* Wi    = (const float*)d_in[4];
  const float* bip   = (const float*)d_in[5];
  const float* Wc    = (const float*)d_in[6];
  const float* bcp   = (const float*)d_in[7];
  const float* Wo    = (const float*)d_in[8];
  const float* bop   = (const float*)d_in[9];
  const float* Wout  = (const float*)d_in[10];
  const float* bout  = (const float*)d_in[11];
  float* out = (float*)d_out;

  char* ws = (char*)d_ws;
  bf16*     WT   = (bf16*)(ws);
  bf16*     embB = (bf16*)(ws + 12582912ull);
  bf16*     hbuf = (bf16*)(ws + 45350912ull);
  unsigned* cnt  = (unsigned*)(ws + 45613056ull);

  k_zero<<<258, 256, 0, stream>>>((unsigned*)(ws + 45350912ull), 65792);
  k_wt<<<dim3(24, 16, 4), 256, 0, stream>>>(Wf, Wi, Wc, Wo, WT);
  k_cvt<<<8000, 256, 0, stream>>>(embed, embB);
  k_lstm<<<256, 256, 0, stream>>>(ids, embB, WT, bfp, bip, bcp, bop, hbuf, cnt);
  k_final<<<dim3(125, 2), 256, 0, stream>>>(hbuf, Wout, bout, out);
}

// Round 6
// 3611.724 us; speedup vs baseline: 3.5534x; 1.0329x over previous
//
#include <hip/hip_runtime.h>
#include <math.h>

typedef __bf16 bf16;
typedef unsigned long long ull;
typedef __attribute__((ext_vector_type(8))) __bf16 bf16x8;
typedef __attribute__((ext_vector_type(4))) float f32x4;

__global__ __launch_bounds__(256) void k_zero(unsigned* __restrict__ p, int n) {
  int i = blockIdx.x * 256 + threadIdx.x;
  if (i < n) p[i] = 0u;
}

// Gate-interleaved packed weights:
//   WT[row][k],  row = (j>>2)*16 + g*4 + (j&3),  j in [0,1024), g in [0,4)
// so that MFMA B-fragment n-index = g*4 + (j&3) within a wave's 4-column slice.
__global__ __launch_bounds__(256) void k_wt(const float* __restrict__ Wf,
                                            const float* __restrict__ Wi,
                                            const float* __restrict__ Wc,
                                            const float* __restrict__ Wo,
                                            bf16* __restrict__ WT) {
  __shared__ __align__(16) float tile[64][68];
  int g = blockIdx.z;
  const float* src = g == 0 ? Wf : g == 1 ? Wi : g == 2 ? Wc : Wo;
  int t = threadIdx.x;
  int r0 = blockIdx.x * 64, c0 = blockIdx.y * 64;   // r: k (1536), c: j (1024)
  int r = t >> 2, cs = (t & 3) * 16;
  const f32x4* s = (const f32x4*)(src + (size_t)(r0 + r) * 1024 + c0 + cs);
#pragma unroll
  for (int i = 0; i < 4; i++) *(f32x4*)&tile[r][cs + i * 4] = s[i];
  __syncthreads();
  int c = t >> 2, rs = (t & 3) * 16;
  bf16x8 v0, v1;
#pragma unroll
  for (int i = 0; i < 8; i++) v0[i] = (bf16)tile[rs + i][c];
#pragma unroll
  for (int i = 0; i < 8; i++) v1[i] = (bf16)tile[rs + 8 + i][c];
  int j = c0 + c;
  size_t row = (size_t)(j >> 2) * 16 + g * 4 + (j & 3);
  bf16* d = WT + row * 1536 + r0 + rs;
  *(bf16x8*)d       = v0;
  *(bf16x8*)(d + 8) = v1;
}

__global__ __launch_bounds__(256) void k_cvt(const float* __restrict__ src,
                                             bf16* __restrict__ dst) {
  size_t i = ((size_t)blockIdx.x * 256 + threadIdx.x) * 8;
  f32x4 a = *(const f32x4*)(src + i);
  f32x4 b = *(const f32x4*)(src + i + 4);
  bf16x8 o;
#pragma unroll
  for (int r = 0; r < 4; r++) { o[r] = (bf16)a[r]; o[4 + r] = (bf16)b[r]; }
  *(bf16x8*)(dst + i) = o;
}

// ---------------------------------------------------------------------------
// Persistent LSTM.  256 blocks = 4 batch-groups x 64 column-owner blocks.
// Wave w owns columns j0 + w*4 .. +4, ALL 4 gates (n = gate*4 + col).
// Pointwise update via intra-wave __shfl (no LDS gate exchange).
// Sync: per-block flag array (parallel stores, vector poll) — no RMW hotspot.
// x-projection of step t+1 pipelined into the barrier window.
// ---------------------------------------------------------------------------
__global__ __launch_bounds__(256, 1) void k_lstm(const int* __restrict__ ids,
                                                 const bf16* __restrict__ embB,
                                                 const bf16* __restrict__ WT,
                                                 const float* __restrict__ bfp,
                                                 const float* __restrict__ bip,
                                                 const float* __restrict__ bcp,
                                                 const float* __restrict__ bop,
                                                 bf16* __restrict__ hbuf,
                                                 unsigned* __restrict__ flags_all) {
  int blk = blockIdx.x;
  int gb = blk >> 6, wgid = blk & 63, j0 = wgid * 16;
  int t = threadIdx.x, l = t & 63, w = t >> 6;
  int q = l >> 4, rl = l & 15;
  __shared__ __align__(16) bf16 sx[16 * 520];
  __shared__ __align__(16) bf16 sh[16 * 1032];
  __shared__ __align__(16) bf16 hw[4][16][4];

  // weights: packed row = (wgid*4 + w)*16 + rl
  const bf16* wrow = WT + ((size_t)(wgid * 4 + w) * 16 + rl) * 1536;
  bf16x8 wx[16], wh[32];
#pragma unroll
  for (int ks = 0; ks < 16; ++ks) wx[ks] = *(const bf16x8*)(wrow + ks * 32 + q * 8);
#pragma unroll
  for (int ks = 0; ks < 32; ++ks) wh[ks] = *(const bf16x8*)(wrow + 512 + ks * 32 + q * 8);

  int gate = rl >> 2;
  int jcol = j0 + w * 4 + (rl & 3);
  const float* bias_p = gate == 0 ? bfp : gate == 1 ? bip : gate == 2 ? bcp : bop;
  float bv = bias_p[jcol];

  unsigned* flags = flags_all + gb * 64;
  float creg[4] = {0.f, 0.f, 0.f, 0.f};

  // ---- prologue: stage x(0), compute its MFMAs ----
  f32x4 xa0 = {0.f, 0.f, 0.f, 0.f}, xa1 = {0.f, 0.f, 0.f, 0.f};
#pragma unroll
  for (int i = 0; i < 4; i++) {
    int c = i * 256 + t;
    int mm = c >> 6, kc = c & 63;
    int tok = ids[(gb * 16 + mm) * 512 + 0];
    *(bf16x8*)(sx + mm * 520 + kc * 8) =
        *(const bf16x8*)(embB + (size_t)tok * 512 + kc * 8);
  }
  __syncthreads();
  {
    const bf16* xrow = sx + rl * 520;
#pragma unroll
    for (int ks = 0; ks < 16; ks += 2) {
      bf16x8 a0 = *(const bf16x8*)(xrow + ks * 32 + q * 8);
      bf16x8 a1 = *(const bf16x8*)(xrow + (ks + 1) * 32 + q * 8);
      xa0 = __builtin_amdgcn_mfma_f32_16x16x32_bf16(a0, wx[ks], xa0, 0, 0, 0);
      xa1 = __builtin_amdgcn_mfma_f32_16x16x32_bf16(a1, wx[ks + 1], xa1, 0, 0, 0);
    }
  }

  for (int ts = 0; ts < 512; ++ts) {
    const bf16* rbuf = hbuf + (ts & 1) * 65536;
    bf16* wbuf = hbuf + ((ts + 1) & 1) * 65536;

    __syncthreads();                                   // S_a: sh free to overwrite
    // stage h slab [16][1024]: paired coherent 8B loads -> one b128 LDS write
#pragma unroll
    for (int i = 0; i < 8; i++) {
      int chunk = i * 256 + t;                         // 16B chunks
      int mm = chunk >> 7, kc8 = (chunk & 127) * 8;    // bf16 units
      const ull* gp = (const ull*)(rbuf + (size_t)(gb * 16 + mm) * 1024 + kc8);
      ull a = __hip_atomic_load(gp,     __ATOMIC_RELAXED, __HIP_MEMORY_SCOPE_AGENT);
      ull b = __hip_atomic_load(gp + 1, __ATOMIC_RELAXED, __HIP_MEMORY_SCOPE_AGENT);
      ull* lp = (ull*)(sh + mm * 1032 + kc8);
      lp[0] = a; lp[1] = b;
    }
    __syncthreads();                                   // S_b: sh ready

    // h-part MFMAs (4 chains) on top of pipelined x accumulators
    f32x4 h0 = {0.f,0.f,0.f,0.f}, h1 = {0.f,0.f,0.f,0.f};
    f32x4 h2 = {0.f,0.f,0.f,0.f}, h3 = {0.f,0.f,0.f,0.f};
    {
      const bf16* hrow = sh + rl * 1032;
#pragma unroll
      for (int ks = 0; ks < 32; ks += 4) {
        bf16x8 a0 = *(const bf16x8*)(hrow + ks * 32 + q * 8);
        bf16x8 a1 = *(const bf16x8*)(hrow + (ks + 1) * 32 + q * 8);
        bf16x8 a2 = *(const bf16x8*)(hrow + (ks + 2) * 32 + q * 8);
        bf16x8 a3 = *(const bf16x8*)(hrow + (ks + 3) * 32 + q * 8);
        h0 = __builtin_amdgcn_mfma_f32_16x16x32_bf16(a0, wh[ks],     h0, 0, 0, 0);
        h1 = __builtin_amdgcn_mfma_f32_16x16x32_bf16(a1, wh[ks + 1], h1, 0, 0, 0);
        h2 = __builtin_amdgcn_mfma_f32_16x16x32_bf16(a2, wh[ks + 2], h2, 0, 0, 0);
        h3 = __builtin_amdgcn_mfma_f32_16x16x32_bf16(a3, wh[ks + 3], h3, 0, 0, 0);
      }
    }
    f32x4 pre = ((xa0 + xa1) + (h0 + h1)) + (h2 + h3);

    // activation: lane's gate
    f32x4 av;
    if (gate == 2) {
#pragma unroll
      for (int r = 0; r < 4; r++) {
        float x = fminf(fmaxf(pre[r] + bv, -20.f), 20.f);
        float e = __expf(-2.f * x);
        av[r] = (1.f - e) / (1.f + e);
      }
    } else {
#pragma unroll
      for (int r = 0; r < 4; r++) {
        float x = fminf(fmaxf(pre[r] + bv, -30.f), 30.f);
        av[r] = 1.f / (1.f + __expf(-x));
      }
    }

    // intra-wave gate exchange + pointwise (4x redundant across gates)
    int base = (l & 48) | (l & 3);
    bf16x8 hv8;
#pragma unroll
    for (int r = 0; r < 4; r++) {
      float fg = __shfl(av[r], base,      64);
      float ig = __shfl(av[r], base + 4,  64);
      float gg = __shfl(av[r], base + 8,  64);
      float og = __shfl(av[r], base + 12, 64);
      creg[r] = creg[r] * fg + gg * ig;
      hv8[r] = (bf16)(creg[r] * og);
    }
    // gate-0 lanes deposit h into wave-local LDS, 16 lanes publish 8B each
    if (rl < 4) {
#pragma unroll
      for (int r = 0; r < 4; r++) hw[w][q * 4 + r][rl] = hv8[r];
    }
    if (l < 16) {
      ull v = *(const ull*)&hw[w][l][0];
      __hip_atomic_store((ull*)(wbuf + (size_t)(gb * 16 + l) * 1024 + j0 + w * 4),
                         v, __ATOMIC_RELAXED, __HIP_MEMORY_SCOPE_AGENT);
    }

    // stage x slab for ts+1 (covered by S_c)
    if (ts < 511) {
#pragma unroll
      for (int i = 0; i < 4; i++) {
        int c = i * 256 + t;
        int mm = c >> 6, kc = c & 63;
        int tok = ids[(gb * 16 + mm) * 512 + ts + 1];
        *(bf16x8*)(sx + mm * 520 + kc * 8) =
            *(const bf16x8*)(embB + (size_t)tok * 512 + kc * 8);
      }
    }
    __syncthreads();                                   // S_c: drains h stores + sx
    if (t == 0)
      __hip_atomic_store(flags + wgid, (unsigned)(ts + 1),
                         __ATOMIC_RELAXED, __HIP_MEMORY_SCOPE_AGENT);

    // x-part MFMAs for ts+1 (overlaps flag propagation)
    if (ts < 511) {
      xa0 = {0.f, 0.f, 0.f, 0.f}; xa1 = {0.f, 0.f, 0.f, 0.f};
      const bf16* xrow = sx + rl * 520;
#pragma unroll
      for (int ks = 0; ks < 16; ks += 2) {
        bf16x8 a0 = *(const bf16x8*)(xrow + ks * 32 + q * 8);
        bf16x8 a1 = *(const bf16x8*)(xrow + (ks + 1) * 32 + q * 8);
        xa0 = __builtin_amdgcn_mfma_f32_16x16x32_bf16(a0, wx[ks], xa0, 0, 0, 0);
        xa1 = __builtin_amdgcn_mfma_f32_16x16x32_bf16(a1, wx[ks + 1], xa1, 0, 0, 0);
      }
      // wave 0 polls all 64 producer flags with one vector load per spin
      if (w == 0) {
        unsigned tgt = (unsigned)(ts + 1);
        for (;;) {
          unsigned v = __hip_atomic_load(flags + l, __ATOMIC_RELAXED,
                                         __HIP_MEMORY_SCOPE_AGENT);
          if (__ballot(v >= tgt) == ~0ull) break;
          __builtin_amdgcn_s_sleep(1);
        }
      }
    }
    // S_a of next iteration gates everyone on wave 0's poll
  }
}

// ---------------------------------------------------------------------------
// Final logits, fp32 VALU: out[b][v] = sum_k h[b][k]*Wout[k][v] + bout[v].
// ---------------------------------------------------------------------------
__global__ __launch_bounds__(256) void k_final(const bf16* __restrict__ h,
                                               const float* __restrict__ Wout,
                                               const float* __restrict__ boutp,
                                               float* __restrict__ out) {
  int t = threadIdx.x;
  int v = blockIdx.x * 256 + t;
  int b0 = blockIdx.y * 32;
  __shared__ __align__(16) bf16 shf[32 * 1024];
#pragma unroll
  for (int i = 0; i < 16; i++) {
    int c = i * 256 + t;
    int mm = c >> 7, kc = c & 127;
    *(bf16x8*)(shf + mm * 1024 + kc * 8) =
        *(const bf16x8*)(h + (size_t)(b0 + mm) * 1024 + kc * 8);
  }
  __syncthreads();
  float acc[32];
  float bb = boutp[v];
#pragma unroll
  for (int mm = 0; mm < 32; mm++) acc[mm] = bb;
  for (int k = 0; k < 1024; k++) {
    float wv = Wout[(size_t)k * 32000 + v];
#pragma unroll
    for (int mm = 0; mm < 32; mm++) acc[mm] += (float)shf[mm * 1024 + k] * wv;
  }
#pragma unroll
  for (int mm = 0; mm < 32; mm++)
    out[(size_t)(b0 + mm) * 32000 + v] = acc[mm];
}

// ---------------------------------------------------------------------------
// Workspace (bytes), total 45,614,080:
//   WT    @ 0        : 4096*1536*2  = 12,582,912  (gate-interleaved packed)
//   embB  @ 12582912 : 32000*512*2  = 32,768,000
//   hbuf  @ 45350912 : 2*64*1024*2  =    262,144  (zeroed)
//   flags @ 45613056 : 4 groups * 64 * 4B = 1024  (zeroed)
// ---------------------------------------------------------------------------
extern "C" void kernel_launch(void* const* d_in, const int* in_sizes, int n_in,
                              void* d_out, int out_size, void* d_ws, size_t ws_size,
                              hipStream_t stream) {
  const int*   ids   = (const int*)d_in[0];
  const float* embed = (const float*)d_in[1];
  const float* Wf    = (const float*)d_in[2];
  const float* bfp   = (const float*)d_in[3];
  const float* Wi    = (const float*)d_in[4];
  const float* bip   = (const float*)d_in[5];
  const float* Wc    = (const float*)d_in[6];
  const float* bcp   = (const float*)d_in[7];
  const float* Wo    = (const float*)d_in[8];
  const float* bop   = (const float*)d_in[9];
  const float* Wout  = (const float*)d_in[10];
  const float* bout  = (const float*)d_in[11];
  float* out = (float*)d_out;

  char* ws = (char*)d_ws;
  bf16*     WT    = (bf16*)(ws);
  bf16*     embB  = (bf16*)(ws + 12582912ull);
  bf16*     hbuf  = (bf16*)(ws + 45350912ull);
  unsigned* flags = (unsigned*)(ws + 45613056ull);

  k_zero<<<258, 256, 0, stream>>>((unsigned*)(ws + 45350912ull), 65792);
  k_wt<<<dim3(24, 16, 4), 256, 0, stream>>>(Wf, Wi, Wc, Wo, WT);
  k_cvt<<<8000, 256, 0, stream>>>(embed, embB);
  k_lstm<<<256, 256, 0, stream>>>(ids, embB, WT, bfp, bip, bcp, bop, hbuf, flags);
  k_final<<<dim3(125, 2), 256, 0, stream>>>(hbuf, Wout, bout, out);
}